// Round 1
// baseline (127.089 us; speedup 1.0000x reference)
//
#include <hip/hip_runtime.h>
#include <hip/hip_bf16.h>
#include <math.h>

// Problem constants
constexpr int NB    = 4;      // batch
constexpr int NHID  = 4096;
constexpr int NHEAD = 32;
constexpr int NKV   = 8;
constexpr int NGQ   = 4;      // heads per kv group
constexpr int ND    = 128;
constexpr int NS    = 16384;
constexpr int NPG   = 64;     // page size
constexpr int NP    = 256;    // num pages
constexpr int NTOP  = 64;
constexpr int NSPLIT = 32;    // flash-decode splits
constexpr int PPS   = NTOP / NSPLIT;  // pages per split = 2
constexpr float FSCALE = 0.08838834764831845f; // 1/sqrt(128)

// ---------------------------------------------------------------------------
// K1: QKV projection. qkv[b*6144 + row] = dot(Wrow, hidden[b]).
// rows 0..4095 -> Wq, 4096..5119 -> Wk, 5120..6143 -> Wv.
// 4 rows per block, 256 threads, shared hidden reads (float4).
// ---------------------------------------------------------------------------
__global__ __launch_bounds__(256) void k_qkv(
    const float* __restrict__ hs, const float* __restrict__ Wq,
    const float* __restrict__ Wk, const float* __restrict__ Wv,
    float* __restrict__ qkv) {
  int row0 = blockIdx.x * 4;
  int t = threadIdx.x;
  const float4* x4 = (const float4*)hs;
  const float4* wr[4];
#pragma unroll
  for (int r = 0; r < 4; r++) {
    int row = row0 + r;
    const float* w;
    if (row < 4096)      w = Wq + (size_t)row * NHID;
    else if (row < 5120) w = Wk + (size_t)(row - 4096) * NHID;
    else                 w = Wv + (size_t)(row - 5120) * NHID;
    wr[r] = (const float4*)w;
  }
  float acc[4][4] = {};
  for (int j = t; j < NHID / 4; j += 256) {
    float4 x0 = x4[j], x1 = x4[1024 + j], x2 = x4[2048 + j], x3 = x4[3072 + j];
#pragma unroll
    for (int r = 0; r < 4; r++) {
      float4 w4 = wr[r][j];
      acc[r][0] += w4.x * x0.x + w4.y * x0.y + w4.z * x0.z + w4.w * x0.w;
      acc[r][1] += w4.x * x1.x + w4.y * x1.y + w4.z * x1.z + w4.w * x1.w;
      acc[r][2] += w4.x * x2.x + w4.y * x2.y + w4.z * x2.z + w4.w * x2.w;
      acc[r][3] += w4.x * x3.x + w4.y * x3.y + w4.z * x3.z + w4.w * x3.w;
    }
  }
  __shared__ float red[4][16];
  int lane = t & 63, wv = t >> 6;
#pragma unroll
  for (int r = 0; r < 4; r++)
#pragma unroll
    for (int b = 0; b < 4; b++) {
      float v = acc[r][b];
      v += __shfl_down(v, 32); v += __shfl_down(v, 16); v += __shfl_down(v, 8);
      v += __shfl_down(v, 4);  v += __shfl_down(v, 2);  v += __shfl_down(v, 1);
      if (lane == 0) red[wv][r * 4 + b] = v;
    }
  __syncthreads();
  if (t < 16) {
    int r = t >> 2, b = t & 3;
    float s = red[0][t] + red[1][t] + red[2][t] + red[3][t];
    qkv[(size_t)b * 6144 + row0 + r] = s;
  }
}

// ---------------------------------------------------------------------------
// K2: RoPE on q and k_new, copy v_new, and group-mean q -> qm.
// One block per (b, kv). 256 threads = 4 q-heads x 64 rotation pairs.
// ---------------------------------------------------------------------------
__global__ __launch_bounds__(256) void k_rope_merge(
    const float* __restrict__ qkv, const float* __restrict__ cosp,
    const float* __restrict__ sinp, float* __restrict__ qr,
    float* __restrict__ kn, float* __restrict__ vn, float* __restrict__ qm) {
  int b = blockIdx.x >> 3, kv = blockIdx.x & 7;
  const float* cs = cosp + b * ND;
  const float* sn = sinp + b * ND;
  int t = threadIdx.x;
  int g = t >> 6, i = t & 63;
  __shared__ float sq[4][ND];
  {
    int h = kv * NGQ + g;
    const float* q = qkv + (size_t)b * 6144 + h * ND;
    float x1 = q[i], x2 = q[i + 64];
    float o1 = x1 * cs[i] - x2 * sn[i];
    float o2 = x2 * cs[i + 64] + x1 * sn[i + 64];
    float* dst = qr + ((size_t)b * NHEAD + h) * ND;
    dst[i] = o1; dst[i + 64] = o2;
    sq[g][i] = o1; sq[g][i + 64] = o2;
  }
  if (t < 64) {
    const float* k = qkv + (size_t)b * 6144 + 4096 + kv * ND;
    float x1 = k[t], x2 = k[t + 64];
    float* dst = kn + ((size_t)b * NKV + kv) * ND;
    dst[t] = x1 * cs[t] - x2 * sn[t];
    dst[t + 64] = x2 * cs[t + 64] + x1 * sn[t + 64];
  }
  if (t < 128) {
    vn[((size_t)b * NKV + kv) * ND + t] = qkv[(size_t)b * 6144 + 5120 + kv * ND + t];
  }
  __syncthreads();
  if (t < 128) {
    qm[((size_t)b * NKV + kv) * ND + t] =
        0.25f * (sq[0][t] + sq[1][t] + sq[2][t] + sq[3][t]);
  }
}

// ---------------------------------------------------------------------------
// K3: per-page min/max + score. One block per (b,kv,page); 256 threads =
// 128 cols x 2 row-halves. score = sum_d max(qm*kmin, qm*kmax).
// ---------------------------------------------------------------------------
__global__ __launch_bounds__(256) void k_pagescore(
    const float* __restrict__ kc, const float* __restrict__ qm,
    float* __restrict__ scores) {
  int bid = blockIdx.x;
  int p = bid & (NP - 1);
  int bh = bid >> 8;                 // b*8+kv
  const float* base = kc + ((size_t)bh * NS + (size_t)p * NPG) * ND;
  int t = threadIdx.x, c = t & 127, hlf = t >> 7;
  float mn = INFINITY, mx = -INFINITY;
  const float* ptr = base + (size_t)hlf * 32 * ND + c;
  for (int r = 0; r < 32; r++) {
    float v = ptr[(size_t)r * ND];
    mn = fminf(mn, v); mx = fmaxf(mx, v);
  }
  __shared__ float smn[256], smx[256], ssc[128];
  smn[t] = mn; smx[t] = mx;
  __syncthreads();
  if (t < 128) {
    float qv = qm[(size_t)bh * ND + t];
    float lo = fminf(smn[t], smn[t + 128]);
    float hi = fmaxf(smx[t], smx[t + 128]);
    ssc[t] = fmaxf(qv * lo, qv * hi);
  }
  __syncthreads();
  if (t < 64) {
    float s = ssc[t] + ssc[t + 64];
    s += __shfl_down(s, 32); s += __shfl_down(s, 16); s += __shfl_down(s, 8);
    s += __shfl_down(s, 4);  s += __shfl_down(s, 2);  s += __shfl_down(s, 1);
    if (t == 0) scores[bid] = s;
  }
}

// ---------------------------------------------------------------------------
// K4: top-64 of 256 scores per (b,kv) via rank counting.
// Tie-break (equal score -> lower index wins) matches jax.lax.top_k set.
// ---------------------------------------------------------------------------
__global__ __launch_bounds__(256) void k_topk(
    const float* __restrict__ scores, int* __restrict__ sel) {
  int bh = blockIdx.x;
  int t = threadIdx.x;
  __shared__ float s[256];
  s[t] = scores[(size_t)bh * NP + t];
  __syncthreads();
  float mine = s[t];
  int rank = 0;
  for (int j = 0; j < 256; j++) {
    float v = s[j];
    rank += (v > mine) || (v == mine && j < t);
  }
  if (rank < NTOP) sel[(size_t)bh * NTOP + rank] = t;
}

// ---------------------------------------------------------------------------
// K5: flash-decode partials over selected pages. Grid = (b*8+kv)*NSPLIT+sp.
// 4 waves = 4 query heads of the group. Within a wave: half-wave per row,
// 32 lanes x float4 cols, xor-reduce. Softmax with fixed m=0 (|logit|<~15,
// exp cannot overflow), so partial = (sum_w, sum_w*V).
// ---------------------------------------------------------------------------
__global__ __launch_bounds__(256) void k_attn_part(
    const float* __restrict__ kc, const float* __restrict__ vc,
    const float* __restrict__ qr, const int* __restrict__ sel,
    float* __restrict__ part_l, float* __restrict__ part_o) {
  int idx = blockIdx.x;
  int sp = idx & (NSPLIT - 1);
  int bh = idx / NSPLIT;              // b*8+kv
  int b = bh >> 3, kv = bh & 7;
  int t = threadIdx.x;
  int g = t >> 6, lane = t & 63;
  int h = kv * NGQ + g;
  int half = lane >> 5;               // 0: even rows, 1: odd rows
  int li = lane & 31;                 // col block (4 floats)
  const float4* q4 = (const float4*)(qr + ((size_t)b * NHEAD + h) * ND);
  float4 qv = q4[li];
  float lsum = 0.f;
  float4 o = make_float4(0.f, 0.f, 0.f, 0.f);
#pragma unroll
  for (int pi = 0; pi < PPS; pi++) {
    int page = sel[(size_t)bh * NTOP + sp * PPS + pi];
    const float4* Kp = (const float4*)(kc + ((size_t)bh * NS + (size_t)page * NPG) * ND);
    const float4* Vp = (const float4*)(vc + ((size_t)bh * NS + (size_t)page * NPG) * ND);
    for (int r2 = 0; r2 < NPG / 2; r2++) {
      int r = r2 * 2 + half;
      float4 kk = Kp[r * 32 + li];
      float d = kk.x * qv.x + kk.y * qv.y + kk.z * qv.z + kk.w * qv.w;
      d += __shfl_xor(d, 1); d += __shfl_xor(d, 2); d += __shfl_xor(d, 4);
      d += __shfl_xor(d, 8); d += __shfl_xor(d, 16);
      float w = __expf(d * FSCALE);
      lsum += w;
      float4 vv = Vp[r * 32 + li];
      o.x += w * vv.x; o.y += w * vv.y; o.z += w * vv.z; o.w += w * vv.w;
    }
  }
  // combine even/odd row halves (lane ^ 32 holds same cols, other rows)
  o.x += __shfl_xor(o.x, 32); o.y += __shfl_xor(o.y, 32);
  o.z += __shfl_xor(o.z, 32); o.w += __shfl_xor(o.w, 32);
  lsum += __shfl_xor(lsum, 32);
  if (half == 0) {
    float4* po = (float4*)(part_o + (((size_t)bh * NGQ + g) * NSPLIT + sp) * ND);
    po[li] = o;
    if (li == 0) part_l[((size_t)bh * NGQ + g) * NSPLIT + sp] = lsum;
  }
}

// ---------------------------------------------------------------------------
// K6: combine partials + the appended (k_new, v_new) row; normalize.
// One wave per (b, h).
// ---------------------------------------------------------------------------
__global__ __launch_bounds__(64) void k_combine(
    const float* __restrict__ qr, const float* __restrict__ kn,
    const float* __restrict__ vn, const float* __restrict__ part_l,
    const float* __restrict__ part_o, float* __restrict__ attno) {
  int bid = blockIdx.x;                // b*32 + h
  int b = bid >> 5, h = bid & 31;
  int kv = h >> 2, g = h & 3;
  int lane = threadIdx.x;
  int bh = b * NKV + kv;
  const float2* q2 = (const float2*)(qr + ((size_t)b * NHEAD + h) * ND);
  const float2* k2 = (const float2*)(kn + (size_t)bh * ND);
  float2 qv = q2[lane], kk = k2[lane];
  float d = qv.x * kk.x + qv.y * kk.y;
  d += __shfl_xor(d, 1); d += __shfl_xor(d, 2); d += __shfl_xor(d, 4);
  d += __shfl_xor(d, 8); d += __shfl_xor(d, 16); d += __shfl_xor(d, 32);
  float wn = __expf(d * FSCALE);
  const float2* v2 = (const float2*)(vn + (size_t)bh * ND);
  float2 vv = v2[lane];
  float ox = wn * vv.x, oy = wn * vv.y, lt = wn;
  const float* pl = part_l + ((size_t)bh * NGQ + g) * NSPLIT;
  const float2* po = (const float2*)(part_o + (((size_t)bh * NGQ + g) * NSPLIT) * ND);
  for (int s = 0; s < NSPLIT; s++) {
    lt += pl[s];
    float2 p = po[(size_t)s * 64 + lane];
    ox += p.x; oy += p.y;
  }
  float inv = 1.0f / lt;
  float2* ao = (float2*)(attno + ((size_t)b * NHEAD + h) * ND);
  ao[lane] = make_float2(ox * inv, oy * inv);
}

// ---------------------------------------------------------------------------
// K7: output projection. out[b*4096+row] = dot(Wo[row], attno[b]).
// ---------------------------------------------------------------------------
__global__ __launch_bounds__(256) void k_oproj(
    const float* __restrict__ Wo, const float* __restrict__ x,
    float* __restrict__ out) {
  int row0 = blockIdx.x * 4;
  int t = threadIdx.x;
  const float4* x4 = (const float4*)x;
  float acc[4][4] = {};
  for (int j = t; j < NHID / 4; j += 256) {
    float4 x0 = x4[j], x1 = x4[1024 + j], x2 = x4[2048 + j], x3 = x4[3072 + j];
#pragma unroll
    for (int r = 0; r < 4; r++) {
      float4 w4 = ((const float4*)(Wo + (size_t)(row0 + r) * NHID))[j];
      acc[r][0] += w4.x * x0.x + w4.y * x0.y + w4.z * x0.z + w4.w * x0.w;
      acc[r][1] += w4.x * x1.x + w4.y * x1.y + w4.z * x1.z + w4.w * x1.w;
      acc[r][2] += w4.x * x2.x + w4.y * x2.y + w4.z * x2.z + w4.w * x2.w;
      acc[r][3] += w4.x * x3.x + w4.y * x3.y + w4.z * x3.z + w4.w * x3.w;
    }
  }
  __shared__ float red[4][16];
  int lane = t & 63, wv = t >> 6;
#pragma unroll
  for (int r = 0; r < 4; r++)
#pragma unroll
    for (int b = 0; b < 4; b++) {
      float v = acc[r][b];
      v += __shfl_down(v, 32); v += __shfl_down(v, 16); v += __shfl_down(v, 8);
      v += __shfl_down(v, 4);  v += __shfl_down(v, 2);  v += __shfl_down(v, 1);
      if (lane == 0) red[wv][r * 4 + b] = v;
    }
  __syncthreads();
  if (t < 16) {
    int r = t >> 2, b = t & 3;
    float s = red[0][t] + red[1][t] + red[2][t] + red[3][t];
    out[(size_t)b * NHID + row0 + r] = s;
  }
}

// ---------------------------------------------------------------------------
extern "C" void kernel_launch(void* const* d_in, const int* in_sizes, int n_in,
                              void* d_out, int out_size, void* d_ws, size_t ws_size,
                              hipStream_t stream) {
  const float* hs   = (const float*)d_in[0];
  const float* cosp = (const float*)d_in[1];
  const float* sinp = (const float*)d_in[2];
  const float* kc   = (const float*)d_in[3];
  const float* vc   = (const float*)d_in[4];
  const float* Wq   = (const float*)d_in[5];
  const float* Wk   = (const float*)d_in[6];
  const float* Wv   = (const float*)d_in[7];
  const float* Wo   = (const float*)d_in[8];
  float* out = (float*)d_out;

  float* ws = (float*)d_ws;
  float* qkv    = ws;                 // 24576 floats
  float* qr     = ws + 24576;         // 16384
  float* kn     = ws + 40960;         // 4096
  float* vn     = ws + 45056;         // 4096
  float* qm     = ws + 49152;         // 4096
  float* scores = ws + 53248;         // 8192
  int*   sel    = (int*)(ws + 61440); // 2048 ints
  float* part_l = ws + 63488;         // 4096
  float* part_o = ws + 67584;         // 524288
  float* attno  = ws + 591872;        // 16384

  k_qkv<<<6144 / 4, 256, 0, stream>>>(hs, Wq, Wk, Wv, qkv);
  k_rope_merge<<<NB * NKV, 256, 0, stream>>>(qkv, cosp, sinp, qr, kn, vn, qm);
  k_pagescore<<<NB * NKV * NP, 256, 0, stream>>>(kc, qm, scores);
  k_topk<<<NB * NKV, 256, 0, stream>>>(scores, sel);
  k_attn_part<<<NB * NKV * NSPLIT, 256, 0, stream>>>(kc, vc, qr, sel, part_l, part_o);
  k_combine<<<NB * NHEAD, 64, 0, stream>>>(qr, kn, vn, part_l, part_o, attno);
  k_oproj<<<NHID / 4, 256, 0, stream>>>(Wo, attno, out);
}